// Round 9
// baseline (286.719 us; speedup 1.0000x reference)
//
#include <hip/hip_runtime.h>
#include <hip/hip_bf16.h>

// ---------------------------------------------------------------------------
// Transformer block, B=8 S=1024 H=768 NH=12 HD=64 I=3072.  fp32 in/out,
// bf16 MFMA internals.
// Round 9: GEMM K-loop software-pipelined: fragment ds_reads one tile AHEAD
// into a register double-buffer; ONE barrier per K-tile; each barrier segment
// holds {next-tile ds_reads + stage issue + 16 MFMA} so memory latency hides
// under MFMA (fixes the measured MFMA/memory phase alternation: MfmaUtil 13%,
// VALUBusy 12%, 65% idle).  3 LDS buffers, counted vmcnt(4), setprio.
// attn (swapped-operand softmax) and epilogues unchanged from round 8.
// ---------------------------------------------------------------------------

typedef __attribute__((ext_vector_type(8))) short bf16x8;
typedef __attribute__((ext_vector_type(4))) float f32x4;
typedef const __attribute__((address_space(3))) char* lds_cp;

#define MFMA16(a, b, c) __builtin_amdgcn_mfma_f32_16x16x32_bf16((a), (b), (c), 0, 0, 0)

// inline-asm LDS read: invisible to compiler alias analysis (no auto-vmcnt).
#define DSR(dst, addr, off) \
    asm volatile("ds_read_b128 %0, %1 offset:" #off : "=&v"(dst) : "v"(addr))
#define WAITV4 asm volatile("s_waitcnt vmcnt(4)" ::: "memory")
#define WAITV0 asm volatile("s_waitcnt vmcnt(0)" ::: "memory")
#define WAITLG asm volatile("s_waitcnt lgkmcnt(0)" ::: "memory")
#define SCHEDB __builtin_amdgcn_sched_barrier(0)
// packed f32x2 -> bf16x2 (RNE), single instruction
#define CVTPK(d, lo, hi) \
    asm("v_cvt_pk_bf16_f32 %0, %1, %2" : "=v"(d) : "v"(lo), "v"(hi))

__device__ inline short f2bf(float x) {
    __hip_bfloat16 h = __float2bfloat16(x);
    return *reinterpret_cast<short*>(&h);
}

__device__ inline void gload_lds16(const void* g, void* lds) {
    __builtin_amdgcn_global_load_lds(
        (const __attribute__((address_space(1))) unsigned int*)g,
        (__attribute__((address_space(3))) unsigned int*)lds,
        16, 0, 0);
}

// ---------------------------------------------------------------------------
// Weight prep: W fp32 [K,N] -> Wt bf16 [N,K]   (tiled transpose + cast)
// ---------------------------------------------------------------------------
__global__ __launch_bounds__(256) void transpose_w(
    const float* __restrict__ W, short* __restrict__ Wt, int K, int N) {
    __shared__ float tile[32][33];
    const int tx = threadIdx.x & 31, ty = threadIdx.x >> 5;  // ty 0..7
    const int n0 = blockIdx.x * 32, k0 = blockIdx.y * 32;
#pragma unroll
    for (int i = 0; i < 4; ++i)
        tile[ty + i * 8][tx] = W[(size_t)(k0 + ty + i * 8) * N + n0 + tx];
    __syncthreads();
#pragma unroll
    for (int i = 0; i < 4; ++i)
        Wt[(size_t)(n0 + ty + i * 8) * K + k0 + tx] = f2bf(tile[tx][ty + i * 8]);
}

// ---------------------------------------------------------------------------
// LayerNorm: fp32 [M,768] -> bf16 [M,768]   (one block per row)
// ---------------------------------------------------------------------------
__global__ __launch_bounds__(256) void ln_k(
    const float* __restrict__ x, const float* __restrict__ g,
    const float* __restrict__ b, short* __restrict__ out) {
    const int row = blockIdx.x;
    const int tid = threadIdx.x;
    const float* xr = x + (size_t)row * 768;
    float v[3];
    float s = 0.f, sq = 0.f;
#pragma unroll
    for (int i = 0; i < 3; ++i) {
        v[i] = xr[tid + i * 256];
        s += v[i];
        sq += v[i] * v[i];
    }
#pragma unroll
    for (int off = 32; off >= 1; off >>= 1) {
        s += __shfl_xor(s, off);
        sq += __shfl_xor(sq, off);
    }
    __shared__ float ss[4], ssq[4];
    const int wid = tid >> 6;
    if ((tid & 63) == 0) { ss[wid] = s; ssq[wid] = sq; }
    __syncthreads();
    s = ss[0] + ss[1] + ss[2] + ss[3];
    sq = ssq[0] + ssq[1] + ssq[2] + ssq[3];
    const float mean = s * (1.0f / 768.0f);
    const float var = sq * (1.0f / 768.0f) - mean * mean;  // biased
    const float rstd = rsqrtf(var + 1e-5f);
    short* outr = out + (size_t)row * 768;
#pragma unroll
    for (int i = 0; i < 3; ++i) {
        const int c = tid + i * 256;
        outr[c] = f2bf((v[i] - mean) * rstd * g[c] + b[c]);
    }
}

// ---------------------------------------------------------------------------
// GEMM engine:  C[M,N] = A[M,K](bf16) @ Wt[N,K]^T(bf16) + bias, fused epilogues.
// 128x128 tile, BK=32, 4 waves (2x2), wave = 64x64 out (4x4 16x16 frags).
// Pipelined: sub-iter u = {vmcnt(4); barrier; ds_read tile u+1 -> regNext;
// stage tile u+3; setprio+16 MFMA(tile u, regCur); lgkm(0)+schedb; swap}.
// Tile x lives in LDS buf x%3.  Tail: clamped dummy reads/stages (uniform).
// ---------------------------------------------------------------------------
enum { MODE_BF16 = 0, MODE_QKV = 1, MODE_F32RES = 2, MODE_GELU = 3 };

template <int MODE>
__global__ __launch_bounds__(256) void gemm3p(
    const short* __restrict__ A, const short* __restrict__ Wt,
    const float* __restrict__ bias, const float* __restrict__ resid,
    float* __restrict__ outf, short* __restrict__ outh,
    short* __restrict__ Qo, short* __restrict__ Ko, short* __restrict__ Vto,
    int M, int N, int K) {
    __shared__ __attribute__((aligned(128))) short Al[3][4096];  // [buf][128*32]
    __shared__ __attribute__((aligned(128))) short Bl[3][4096];
    const int tid = threadIdx.x;
    const int lane = tid & 63;
    const int w = tid >> 6;          // 4 waves
    const int wm = w >> 1, wn = w & 1;
    const int m0 = blockIdx.x * 128, n0 = blockIdx.y * 128;

    f32x4 acc[4][4] = {};

    // ---- staging: linear LDS dest, pre-swizzled global source ----
    const int srow = tid >> 2;
    const int scol = ((tid & 3) * 8) ^ (((tid >> 2) & 3) << 3);
    const short* Abase = A + (size_t)(m0 + srow) * K + scol;
    const short* Bbase = Wt + (size_t)(n0 + srow) * K + scol;
    const size_t K64 = (size_t)K * 64;
    short* const AlF = &Al[0][0];
    short* const BlF = &Bl[0][0];

    auto stageT = [&](int boS, int k0s) {  // boS: buffer offset in shorts
        gload_lds16(Abase + k0s,       AlF + boS + w * 512);
        gload_lds16(Abase + K64 + k0s, AlF + boS + 2048 + w * 512);
        gload_lds16(Bbase + k0s,       BlF + boS + w * 512);
        gload_lds16(Bbase + K64 + k0s, BlF + boS + 2048 + w * 512);
    };

    // ---- fragment read offsets (swizzled), bytes within one buffer ----
    const int lrow = lane & 15;
    const int lcolswz = ((lane >> 4) * 16) ^ ((lane & 3) << 4);
    const int aoff = wm * 4096 + lrow * 64 + lcolswz;
    const int boff = wn * 4096 + lrow * 64 + lcolswz;
    const lds_cp AlB = (lds_cp)AlF;
    const lds_cp BlB = (lds_cp)BlF;

    const int NT = K >> 5;
    const int last = NT - 1;

    // register double-buffer for fragments
    bf16x8 ra0, ra1, ra2, ra3, rb0, rb1, rb2, rb3;  // regA set
    bf16x8 sa0, sa1, sa2, sa3, sb0, sb1, sb2, sb3;  // regB set

    // prologue: stage tiles 0,1; tile0 -> regA; stage tile 2
    stageT(0, 0);
    stageT(4096, 32);
    WAITV4;                 // tile 0 landed (tile 1's 4 loads may fly)
    SCHEDB;
    __builtin_amdgcn_s_barrier();
    {
        const lds_cp Ab = AlB + aoff;
        const lds_cp Bb = BlB + boff;
        DSR(ra0, Ab, 0); DSR(ra1, Ab, 1024); DSR(ra2, Ab, 2048); DSR(ra3, Ab, 3072);
        DSR(rb0, Bb, 0); DSR(rb1, Bb, 1024); DSR(rb2, Bb, 2048); DSR(rb3, Bb, 3072);
    }
    stageT(8192, 64);       // tile 2 -> buf2
    WAITLG;                 // regA ready
    SCHEDB;

    // rotating byte offsets: at sub-iter u, read buf (u+1)%3, stage buf u%3
    int rdo = 8192, sto = 0;   // byte offsets within Al/Bl flat arrays
    auto rot = [](int v) { return v == 16384 ? 0 : v + 8192; };

#define GEMM_SUBITER(RA0,RA1,RA2,RA3,RB0,RB1,RB2,RB3, SA0,SA1,SA2,SA3,SB0,SB1,SB2,SB3, U) \
    {                                                                                     \
        WAITV4;                                                                           \
        SCHEDB;                                                                           \
        __builtin_amdgcn_s_barrier();                                                     \
        {                                                                                 \
            int tr = (U) + 1; if (tr > last) tr = last;                                   \
            const int rb_ = (tr % 3) * 8192;                                              \
            const lds_cp Ab = AlB + rb_ + aoff;                                           \
            const lds_cp Bb = BlB + rb_ + boff;                                           \
            DSR(SA0, Ab, 0); DSR(SA1, Ab, 1024); DSR(SA2, Ab, 2048); DSR(SA3, Ab, 3072);  \
            DSR(SB0, Bb, 0); DSR(SB1, Bb, 1024); DSR(SB2, Bb, 2048); DSR(SB3, Bb, 3072);  \
            int ts = (U) + 3; if (ts > last) ts = last;                                   \
            stageT((((U) + 3) % 3) * 4096, ts << 5);                                      \
        }                                                                                 \
        __builtin_amdgcn_s_setprio(1);                                                    \
        {                                                                                 \
            bf16x8 av[4] = {RA0, RA1, RA2, RA3};                                          \
            bf16x8 bv[4] = {RB0, RB1, RB2, RB3};                                          \
            _Pragma("unroll")                                                             \
            for (int mi = 0; mi < 4; ++mi)                                                \
                _Pragma("unroll")                                                         \
                for (int ni = 0; ni < 4; ++ni)                                            \
                    acc[mi][ni] = MFMA16(av[mi], bv[ni], acc[mi][ni]);                    \
        }                                                                                 \
        __builtin_amdgcn_s_setprio(0);                                                    \
        WAITLG;                                                                           \
        SCHEDB;                                                                           \
    }

    for (int t = 0; t < NT; t += 2) {
        // even sub-iter: MFMA tile t (regA), read tile t+1 -> regB
        GEMM_SUBITER(ra0, ra1, ra2, ra3, rb0, rb1, rb2, rb3,
                     sa0, sa1, sa2, sa3, sb0, sb1, sb2, sb3, t);
        // odd sub-iter: MFMA tile t+1 (regB), read tile t+2 -> regA
        GEMM_SUBITER(sa0, sa1, sa2, sa3, sb0, sb1, sb2, sb3,
                     ra0, ra1, ra2, ra3, rb0, rb1, rb2, rb3, t + 1);
        (void)rdo; (void)sto;
    }
#undef GEMM_SUBITER
    WAITV0;  // drain dummy stages before epilogue/endpgm

    // Epilogue.  C/D frag layout: col = lane&15, row = (lane>>4)*4 + r.
#pragma unroll
    for (int mi = 0; mi < 4; ++mi) {
#pragma unroll
        for (int ni = 0; ni < 4; ++ni) {
#pragma unroll
            for (int r = 0; r < 4; ++r) {
                const int row = m0 + wm * 64 + mi * 16 + (lane >> 4) * 4 + r;
                const int col = n0 + wn * 64 + ni * 16 + (lane & 15);
                float v = acc[mi][ni][r] + bias[col];
                if constexpr (MODE == MODE_BF16) {
                    outh[(size_t)row * N + col] = f2bf(v);
                } else if constexpr (MODE == MODE_GELU) {
                    // 0.5v(1+tanh(u)) == v*sigmoid(2u)
                    const float u = 0.7978845608028654f * (v + 0.044715f * v * v * v);
                    const float gl = v / (1.0f + __expf(-2.0f * u));
                    outh[(size_t)row * N + col] = f2bf(gl);
                } else if constexpr (MODE == MODE_F32RES) {
                    outf[(size_t)row * N + col] = v + resid[(size_t)row * N + col];
                } else {  // MODE_QKV: scatter into Q[B,NH,S,HD] (pre-scaled by
                          // 1/sqrt(HD)), K[B,NH,S,HD], Vt[B,NH,HD,S]
                    const int bb = row >> 10, s = row & 1023;
                    if (col < 768) {
                        const int hh = col >> 6, d = col & 63;
                        Qo[(((size_t)(bb * 12 + hh)) * 1024 + s) * 64 + d] = f2bf(v * 0.125f);
                    } else if (col < 1536) {
                        const int c2 = col - 768;
                        const int hh = c2 >> 6, d = c2 & 63;
                        Ko[(((size_t)(bb * 12 + hh)) * 1024 + s) * 64 + d] = f2bf(v);
                    } else {
                        const int c2 = col - 1536;
                        const int hh = c2 >> 6, d = c2 & 63;
                        Vto[(((size_t)(bb * 12 + hh)) * 64 + d) * 1024 + s] = f2bf(v);
                    }
                }
            }
        }
    }
}

// ---------------------------------------------------------------------------
// Flash attention, swapped-operand softmax (unchanged from round 8).
// ---------------------------------------------------------------------------
__global__ __launch_bounds__(256) void attn_k(
    const short* __restrict__ Q, const short* __restrict__ Kg,
    const short* __restrict__ Vtg, short* __restrict__ out) {
    __shared__ __attribute__((aligned(128))) short Kl[2][64 * 64];
    __shared__ __attribute__((aligned(128))) short Vl[2][64 * 64];
    __shared__ __attribute__((aligned(128))) short Pl[4][16 * 64];
    const int tid = threadIdx.x, lane = tid & 63, w = tid >> 6;
    const int swz = (blockIdx.x & 7) * 192 + (blockIdx.x >> 3);
    const int qt = swz & 15, bh = swz >> 4;
    const int b = bh / 12, h = bh % 12;
    const int q0 = qt * 64 + w * 16;
    const int l15 = lane & 15, g = lane >> 4;

    bf16x8 aq[2];
    const short* Qb = Q + ((size_t)bh * 1024 + q0) * 64;
#pragma unroll
    for (int kk = 0; kk < 2; ++kk)
        aq[kk] = *(const bf16x8*)&Qb[(size_t)l15 * 64 + kk * 32 + g * 8];

    float m_run = -1e30f, l_run = 0.f;  // per-lane scalars (q = l15)
    f32x4 o[4] = {};                     // O^T: o[dn][r] = O[d=dn*16+g*4+r][q=l15]

    const short* Kb = Kg + (size_t)bh * 1024 * 64;   // [S][64]
    const short* Vb = Vtg + (size_t)bh * 64 * 1024;  // [64][S]

    const int srr = tid >> 3;
    const int spp = (tid & 7) * 8;
    const int ssc = spp ^ ((srr & 7) << 3);
    auto stage = [&](int buf, int kv0) {
        gload_lds16(Kb + (size_t)(kv0 + srr) * 64 + ssc,        &Kl[buf][w * 512]);
        gload_lds16(Kb + (size_t)(kv0 + 32 + srr) * 64 + ssc,   &Kl[buf][2048 + w * 512]);
        gload_lds16(Vb + (size_t)srr * 1024 + kv0 + ssc,        &Vl[buf][w * 512]);
        gload_lds16(Vb + (size_t)(srr + 32) * 1024 + kv0 + ssc, &Vl[buf][2048 + w * 512]);
    };

    stage(0, 0);
    __syncthreads();

    int buf = 0;
    for (int t = 0; t < 16; ++t) {
        const lds_cp KB = (lds_cp)&Kl[buf][0];
        const lds_cp VB = (lds_cp)&Vl[buf][0];

        bf16x8 kb[4][2];
#pragma unroll
        for (int nk = 0; nk < 4; ++nk) {
            const int R = nk * 16 + l15;
            const int c0 = (g * 8) ^ ((R & 7) << 3);
            const lds_cp a0 = KB + R * 128 + c0 * 2;
            const lds_cp a1 = KB + R * 128 + (c0 ^ 32) * 2;
            DSR(kb[nk][0], a0, 0);
            DSR(kb[nk][1], a1, 0);
        }

        if (t < 15) stage(buf ^ 1, (t + 1) * 64);

        WAITLG;
        SCHEDB;

        f32x4 sc4[4];
#pragma unroll
        for (int nk = 0; nk < 4; ++nk) {
            f32x4 z = {};
            z = MFMA16(kb[nk][0], aq[0], z);
            z = MFMA16(kb[nk][1], aq[1], z);
            sc4[nk] = z;
        }

        float ml = sc4[0][0];
#pragma unroll
        for (int nk = 0; nk < 4; ++nk)
#pragma unroll
            for (int r = 0; r < 4; ++r) ml = fmaxf(ml, sc4[nk][r]);
        ml = fmaxf(ml, __shfl_xor(ml, 16));
        ml = fmaxf(ml, __shfl_xor(ml, 32));
        const float mn = fmaxf(m_run, ml);
        const float alpha = __expf(m_run - mn);
        m_run = mn;
        float padd[4][4];
        float rsum = 0.f;
#pragma unroll
        for (int nk = 0; nk < 4; ++nk)
#pragma unroll
            for (int r = 0; r < 4; ++r) {
                padd[nk][r] = __expf(sc4[nk][r] - mn);
                rsum += padd[nk][r];
            }
        rsum += __shfl_xor(rsum, 16);
        rsum += __shfl_xor(rsum, 32);
        l_run = l_run * alpha + rsum;
#pragma unroll
        for (int dn = 0; dn < 4; ++dn) o[dn] *= alpha;

#pragma unroll
        for (int nk = 0; nk < 4; ++nk) {
            unsigned u0, u1;
            CVTPK(u0, padd[nk][0], padd[nk][1]);
            CVTPK(u1, padd[nk][2], padd[nk][3]);
            const int cc = (nk * 16 + g * 4) ^ ((l15 & 7) << 3);
            uint2 uv; uv.x = u0; uv.y = u1;
            *reinterpret_cast<uint2*>(&Pl[w][l15 * 64 + cc]) = uv;
        }
        bf16x8 pa[2];
#pragma unroll
        for (int kk = 0; kk < 2; ++kk)
            pa[kk] = *(const bf16x8*)&Pl[w][l15 * 64 + ((kk * 32 + g * 8) ^ ((l15 & 7) << 3))];

        bf16x8 vb[4][2];
#pragma unroll
        for (int dn = 0; dn < 4; ++dn) {
            const int R = dn * 16 + l15;
            const int c0 = (g * 8) ^ ((R & 7) << 3);
            const lds_cp a0 = VB + R * 128 + c0 * 2;
            const lds_cp a1 = VB + R * 128 + (c0 ^ 32) * 2;
            DSR(vb[dn][0], a0, 0);
            DSR(vb[dn][1], a1, 0);
        }
        WAITLG;
        SCHEDB;

#pragma unroll
        for (int dn = 0; dn < 4; ++dn) {
            o[dn] = MFMA16(vb[dn][0], pa[0], o[dn]);
            o[dn] = MFMA16(vb[dn][1], pa[1], o[dn]);
        }

        __syncthreads();
        buf ^= 1;
    }

    const float rl = __builtin_amdgcn_rcpf(l_run);
    short* orow = out + ((size_t)(b * 1024) + q0 + l15) * 768 + h * 64;
#pragma unroll
    for (int dn = 0; dn < 4; ++dn) {
        unsigned u0, u1;
        const float v0 = o[dn][0] * rl, v1 = o[dn][1] * rl;
        const float v2 = o[dn][2] * rl, v3 = o[dn][3] * rl;
        CVTPK(u0, v0, v1);
        CVTPK(u1, v2, v3);
        uint2 uv; uv.x = u0; uv.y = u1;
        *reinterpret_cast<uint2*>(&orow[dn * 16 + g * 4]) = uv;
    }
}

// ---------------------------------------------------------------------------
// Launch
// ---------------------------------------------------------------------------
extern "C" void kernel_launch(void* const* d_in, const int* in_sizes, int n_in,
                              void* d_out, int out_size, void* d_ws, size_t ws_size,
                              hipStream_t stream) {
    const float* x      = (const float*)d_in[0];
    const float* ln1_g  = (const float*)d_in[1];
    const float* ln1_b  = (const float*)d_in[2];
    const float* qkv_w  = (const float*)d_in[3];
    const float* qkv_b  = (const float*)d_in[4];
    const float* proj_w = (const float*)d_in[5];
    const float* proj_b = (const float*)d_in[6];
    const float* ln2_g  = (const float*)d_in[7];
    const float* ln2_b  = (const float*)d_in[8];
    const float* fc1_w  = (const float*)d_in[9];
    const float* fc1_b  = (const float*)d_in[10];
    const float* fc2_w  = (const float*)d_in[11];
    const float* fc2_b  = (const float*)d_in[12];
    float* outp = (float*)d_out;

    char* ws = (char*)d_ws;
    size_t off = 0;
    auto alloc = [&](size_t bytes) {
        char* p = ws + off;
        off = (off + bytes + 255) & ~(size_t)255;
        return p;
    };
    short* wt_qkv  = (short*)alloc(2304ull * 768 * 2);
    short* wt_proj = (short*)alloc(768ull * 768 * 2);
    short* wt_fc1  = (short*)alloc(3072ull * 768 * 2);
    short* wt_fc2  = (short*)alloc(768ull * 3072 * 2);
    short* hbuf    = (short*)alloc(8192ull * 768 * 2);
    short* Qb      = (short*)alloc(8192ull * 768 * 2);   // [B,NH,S,HD]
    short* Kbuf    = (short*)alloc(8192ull * 768 * 2);   // [B,NH,S,HD]
    short* Vtb     = (short*)alloc(8192ull * 768 * 2);   // [B,NH,HD,S]
    short* attnb   = (short*)alloc(8192ull * 768 * 2);   // [B,S,H]
    float* x2      = (float*)alloc(8192ull * 768 * 4);   // fp32 residual stream
    short* mfc     = Qb;  // alias: fc1 output [8192,3072] over dead Q/K/Vt/attn
    (void)ws_size; (void)in_sizes; (void)n_in; (void)out_size;

    // weight prep
    transpose_w<<<dim3(2304 / 32, 768 / 32), 256, 0, stream>>>(qkv_w, wt_qkv, 768, 2304);
    transpose_w<<<dim3(768 / 32, 768 / 32), 256, 0, stream>>>(proj_w, wt_proj, 768, 768);
    transpose_w<<<dim3(3072 / 32, 768 / 32), 256, 0, stream>>>(fc1_w, wt_fc1, 768, 3072);
    transpose_w<<<dim3(768 / 32, 3072 / 32), 256, 0, stream>>>(fc2_w, wt_fc2, 3072, 768);

    // attention sublayer
    ln_k<<<8192, 256, 0, stream>>>(x, ln1_g, ln1_b, hbuf);
    gemm3p<MODE_QKV><<<dim3(64, 18), 256, 0, stream>>>(
        hbuf, wt_qkv, qkv_b, nullptr, nullptr, nullptr, Qb, Kbuf, Vtb, 8192, 2304, 768);
    attn_k<<<1536, 256, 0, stream>>>(Qb, Kbuf, Vtb, attnb);
    gemm3p<MODE_F32RES><<<dim3(64, 6), 256, 0, stream>>>(
        attnb, wt_proj, proj_b, x, x2, nullptr, nullptr, nullptr, nullptr, 8192, 768, 768);

    // MLP sublayer
    ln_k<<<8192, 256, 0, stream>>>(x2, ln2_g, ln2_b, hbuf);
    gemm3p<MODE_GELU><<<dim3(64, 24), 256, 0, stream>>>(
        hbuf, wt_fc1, fc1_b, nullptr, nullptr, mfc, nullptr, nullptr, nullptr, 8192, 3072, 768);
    gemm3p<MODE_F32RES><<<dim3(64, 6), 256, 0, stream>>>(
        mfc, wt_fc2, fc2_b, x2, outp, nullptr, nullptr, nullptr, nullptr, 8192, 768, 3072);
}